// Round 11
// baseline (470.261 us; speedup 1.0000x reference)
//
#include <hip/hip_runtime.h>
#include <stdint.h>

// MultiHeadedAttention: B=2,S=2048,D=1024,H=16,DK=64
// Pipeline: fused f32->f16 cvt; fused QKV proj GEMM (MFMA f16, Q scaled
// 0.125); SPLIT-K batch-merged flash attention (grid 1024 = qt x h x
// kv-half -> 4 blocks/CU; bias as MFMA C-operand; partials f16 + m/l f32);
// combine kernel; out proj GEMM -> f32.

typedef _Float16 f16;
typedef _Float16 f16x8 __attribute__((ext_vector_type(8)));
typedef _Float16 f16x4 __attribute__((ext_vector_type(4)));
typedef __fp16 h2 __attribute__((ext_vector_type(2)));
typedef float f32x4 __attribute__((ext_vector_type(4)));

#define LOG2E 1.44269504088896340736f

__device__ __forceinline__ void gload16(const void* g, void* l) {
  __builtin_amdgcn_global_load_lds(
      (const __attribute__((address_space(1))) unsigned int*)g,
      (__attribute__((address_space(3))) unsigned int*)l, 16, 0, 0);
}

// ---------------- fused f32 -> f16 conversion ------------------------------
struct CvtSrcs { const float* s[7]; };

__global__ __launch_bounds__(256) void cvt_all(CvtSrcs a, f16* __restrict__ out) {
  const int i = blockIdx.x * 256 + threadIdx.x;  // 0 .. 4194303
  int r, base;
  if (i < 3145728) { r = i >> 20; base = r << 20; }
  else { r = 3 + ((i - 3145728) >> 18); base = 3145728 + ((r - 3) << 18); }
  const float4 v = ((const float4*)a.s[r])[i - base];
  f16x4 o = {(f16)v.x, (f16)v.y, (f16)v.z, (f16)v.w};
  ((f16x4*)out)[i] = o;
}

// ---------------- mask dtype classify + canonicalize to u8 ----------------
__global__ void mask_detect(const uint8_t* __restrict__ m, int* __restrict__ flag) {
  __shared__ int s_off, s_weird;
  const int t = threadIdx.x;
  if (t == 0) { s_off = 0; s_weird = 0; }
  __syncthreads();
  int f_off = 0, f_weird = 0;
  for (int i = t; i < 8192; i += 256) {
    const uint8_t v = m[i];
    if ((i & 3) && v) f_off = 1;
    if (v > 1) f_weird = 1;
  }
  if (f_off) atomicOr(&s_off, 1);
  if (f_weird) atomicOr(&s_weird, 1);
  __syncthreads();
  if (t == 0) *flag = (s_off && !s_weird) ? 1 : 0;  // 1 => byte-sized bool
}

__global__ __launch_bounds__(256) void mask_canon(const uint8_t* __restrict__ m,
                                                  uint8_t* __restrict__ out,
                                                  const int* __restrict__ flag) {
  const int i = (blockIdx.x * 256 + threadIdx.x) * 4;  // grid covers 8388608
  uchar4 o;
  if (*flag) {
    const uchar4 v = *(const uchar4*)(m + i);
    o = make_uchar4(v.x != 0, v.y != 0, v.z != 0, v.w != 0);
  } else {
    const int4 v = *(const int4*)((const int*)m + i);
    o = make_uchar4(v.x != 0, v.y != 0, v.z != 0, v.w != 0);
  }
  *(uchar4*)(out + i) = o;
}

// ---------------- fused QKV projection GEMM --------------------------------
__global__ __launch_bounds__(256, 2) void gemm_qkv(
    const f16* __restrict__ qh, const f16* __restrict__ kh, const f16* __restrict__ vh,
    const f16* __restrict__ wq, const f16* __restrict__ wk, const f16* __restrict__ wv,
    const float* __restrict__ bq, const float* __restrict__ bk, const float* __restrict__ bv,
    f16* __restrict__ Qp, f16* __restrict__ Kp, f16* __restrict__ Vt) {
  constexpr int K = 1024;
  const int t = threadIdx.x;
  const int w = t >> 6, lane = t & 63, l15 = lane & 15, l4 = lane >> 4;
  const int nt = (int)blockIdx.x % 48;
  const int bm = ((int)blockIdx.x / 48) * 128;
  const int which = nt >> 4;
  const int bn = (nt & 15) * 64;
  const f16* A = which == 0 ? qh : which == 1 ? kh : vh;
  const f16* Bw = which == 0 ? wq : which == 1 ? wk : wv;
  const float* bias = which == 0 ? bq : which == 1 ? bk : bv;

  __shared__ f16 As[2][128 * 32];
  __shared__ f16 Bs[2][64 * 32];

  const f16* a0 = A + (size_t)(bm + (t >> 2)) * K + (t & 3) * 8;
  const f16* a1 = a0 + (size_t)64 * K;
  const f16* b0 = Bw + (size_t)(bn + (t >> 2)) * K + (t & 3) * 8;

  f32x4 acc[2][4];
#pragma unroll
  for (int m = 0; m < 2; ++m)
#pragma unroll
    for (int n = 0; n < 4; ++n) acc[m][n] = (f32x4){0.f, 0.f, 0.f, 0.f};

#define STAGE_G(buf, k0)                          \
  do {                                            \
    gload16(a0 + (k0), &As[buf][w * 512]);        \
    gload16(a1 + (k0), &As[buf][2048 + w * 512]); \
    gload16(b0 + (k0), &Bs[buf][w * 512]);        \
  } while (0)

  STAGE_G(0, 0);
  __syncthreads();
  int cur = 0;
#pragma unroll 1
  for (int kt = 0; kt < 32; ++kt) {
    if (kt < 31) STAGE_G(cur ^ 1, (kt + 1) * 32);
    const f16* ap = &As[cur][(w * 32 + l15) * 32 + l4 * 8];
    const f16* bp = &Bs[cur][l15 * 32 + l4 * 8];
    f16x8 af[2], bfr[4];
#pragma unroll
    for (int m = 0; m < 2; ++m) af[m] = *(const f16x8*)(ap + m * 512);
#pragma unroll
    for (int n = 0; n < 4; ++n) bfr[n] = *(const f16x8*)(bp + n * 512);
#pragma unroll
    for (int m = 0; m < 2; ++m)
#pragma unroll
      for (int n = 0; n < 4; ++n)
        acc[m][n] = __builtin_amdgcn_mfma_f32_16x16x32_f16(af[m], bfr[n], acc[m][n], 0, 0, 0);
    __syncthreads();
    cur ^= 1;
  }
#undef STAGE_G

  const float scale = which == 0 ? 0.125f : 1.0f;
  f16* outp = which == 0 ? Qp : which == 1 ? Kp : Vt;
#pragma unroll
  for (int m = 0; m < 2; ++m) {
    const int r0 = bm + w * 32 + m * 16 + (l4 << 2);
#pragma unroll
    for (int n = 0; n < 4; ++n) {
      const int c = bn + n * 16 + l15;
      const float bv = bias[c];
#pragma unroll
      for (int j = 0; j < 4; ++j) {
        const int r = r0 + j;
        const float v = (acc[m][n][j] + bv) * scale;
        const int b_ = r >> 11, s = r & 2047, h_ = c >> 6, dk = c & 63;
        if (which < 2)
          outp[(((size_t)b_ * 16 + h_) * 2048 + s) * 64 + dk] = (f16)v;
        else
          outp[(((size_t)b_ * 16 + h_) * 64 + dk) * 2048 + s] = (f16)v;
      }
    }
  }
}

// ---------------- output projection GEMM (f32 out) -------------------------
__global__ __launch_bounds__(256, 2) void gemm_out(const f16* __restrict__ A,
                                                   const f16* __restrict__ Bw,
                                                   const float* __restrict__ bias,
                                                   float* __restrict__ outp) {
  constexpr int K = 1024;
  const int t = threadIdx.x;
  const int w = t >> 6, lane = t & 63, l15 = lane & 15, l4 = lane >> 4;
  const int bm = (int)(blockIdx.x >> 4) * 128;
  const int bn = (int)(blockIdx.x & 15) * 64;

  __shared__ f16 As[2][128 * 32];
  __shared__ f16 Bs[2][64 * 32];

  const f16* a0 = A + (size_t)(bm + (t >> 2)) * K + (t & 3) * 8;
  const f16* a1 = a0 + (size_t)64 * K;
  const f16* b0 = Bw + (size_t)(bn + (t >> 2)) * K + (t & 3) * 8;

  f32x4 acc[2][4];
#pragma unroll
  for (int m = 0; m < 2; ++m)
#pragma unroll
    for (int n = 0; n < 4; ++n) acc[m][n] = (f32x4){0.f, 0.f, 0.f, 0.f};

#define STAGE_G(buf, k0)                          \
  do {                                            \
    gload16(a0 + (k0), &As[buf][w * 512]);        \
    gload16(a1 + (k0), &As[buf][2048 + w * 512]); \
    gload16(b0 + (k0), &Bs[buf][w * 512]);        \
  } while (0)

  STAGE_G(0, 0);
  __syncthreads();
  int cur = 0;
#pragma unroll 1
  for (int kt = 0; kt < 32; ++kt) {
    if (kt < 31) STAGE_G(cur ^ 1, (kt + 1) * 32);
    const f16* ap = &As[cur][(w * 32 + l15) * 32 + l4 * 8];
    const f16* bp = &Bs[cur][l15 * 32 + l4 * 8];
    f16x8 af[2], bfr[4];
#pragma unroll
    for (int m = 0; m < 2; ++m) af[m] = *(const f16x8*)(ap + m * 512);
#pragma unroll
    for (int n = 0; n < 4; ++n) bfr[n] = *(const f16x8*)(bp + n * 512);
#pragma unroll
    for (int m = 0; m < 2; ++m)
#pragma unroll
      for (int n = 0; n < 4; ++n)
        acc[m][n] = __builtin_amdgcn_mfma_f32_16x16x32_f16(af[m], bfr[n], acc[m][n], 0, 0, 0);
    __syncthreads();
    cur ^= 1;
  }
#undef STAGE_G

#pragma unroll
  for (int m = 0; m < 2; ++m) {
    const int r0 = bm + w * 32 + m * 16 + (l4 << 2);
#pragma unroll
    for (int n = 0; n < 4; ++n) {
      const int c = bn + n * 16 + l15;
      const float bv = bias[c];
#pragma unroll
      for (int j = 0; j < 4; ++j)
        outp[(size_t)(r0 + j) * 1024 + c] = acc[m][n][j] + bv;
    }
  }
}

// ---------------- split-K batch-merged flash attention ---------------------
// 1024 blocks: bid -> (qt 0..31, h 0..15, half 0..1). Each block: 64 q-rows,
// both batches, kv in [half*1024, half*1024+1024) as 16 tiles of 64.
// Single-buffered K/V (40KB LDS total) -> 4 blocks/CU at launch_bounds(,4).
// Raw-domain scores: Q scaled 0.125; bias enters as the MFMA C-operand
// (bc[n][j] == sacc[n][j] layout); exp via exp2(fmaf(s,L2E,-m*L2E)).
// Partials: O normalized by this half's l (f16) + m,l (f32); merged later.
__device__ __forceinline__ const f16x8* swzr(const f16* base, int row, int bytecol) {
  return (const f16x8*)((const char*)base + row * 128 + (bytecol ^ ((row & 7) << 4)));
}

__global__ __launch_bounds__(256, 4) void attn_fwd(
    const f16* __restrict__ Qp, const f16* __restrict__ Kp,
    const f16* __restrict__ Vt, const float* __restrict__ bias,
    const uint8_t* __restrict__ mask, f16* __restrict__ Op,
    float* __restrict__ mArr, float* __restrict__ lArr) {
  constexpr int S = 2048;
  const int bid = blockIdx.x;
  const int half = bid >> 9;
  const int qt = bid & 31, h = (bid >> 5) & 15;
  const int t = threadIdx.x, w = t >> 6, lane = t & 63;
  const int l15 = lane & 15, l4 = lane >> 4;
  const int q0 = qt * 64 + w * 16;
  const int k0g = half * 1024;

  const f16* Qb0 = Qp + (size_t)h * S * 64;
  const f16* Qb1 = Qp + (size_t)(16 + h) * S * 64;

  __shared__ f16 Ks[2][64 * 64];  // [batch][kv][dk], swizzled (single buf)
  __shared__ f16 Vs[2][64 * 64];  // [batch][dk][kv], swizzled
  __shared__ f16 Ps[4][16 * 64];  // per-wave P, swizzled

  f16x8 qf[2][2];
#pragma unroll
  for (int ks = 0; ks < 2; ++ks) {
    qf[0][ks] = *(const f16x8*)(Qb0 + (size_t)(q0 + l15) * 64 + ks * 32 + l4 * 8);
    qf[1][ks] = *(const f16x8*)(Qb1 + (size_t)(q0 + l15) * 64 + ks * 32 + l4 * 8);
  }

  f32x4 oacc[2][4];
#pragma unroll
  for (int bb = 0; bb < 2; ++bb)
#pragma unroll
    for (int n = 0; n < 4; ++n) oacc[bb][n] = (f32x4){0.f, 0.f, 0.f, 0.f};
  float mrow[2] = {-3e38f, -3e38f}, lrow[2] = {0.f, 0.f};

  // running source pointers (pre-offset by kv half)
  const int srow = t >> 3;
  const int scol = (((t & 7) ^ (srow & 7)) << 3);
  const f16* kp0 = Kp + (size_t)h * S * 64 + (size_t)(k0g + srow) * 64 + scol;
  const f16* kp1 = kp0 + (size_t)16 * S * 64;
  const f16* vp0 = Vt + (size_t)h * 64 * S + (size_t)srow * S + k0g + scol;
  const f16* vp1 = vp0 + (size_t)16 * 64 * S;
  const float* bp = bias + (size_t)h * S * S + (size_t)(q0 + l15) * S + k0g + l4 * 4;
  const uint8_t* mp0 = mask + (size_t)(q0 + l15) * S + k0g + l4 * 4;
  const uint8_t* mp1 = mp0 + (size_t)S * S;

  f32x4 bcA[4], bcB[4];
  uint32_t mcA[2][4], mcB[2][4];

#define STAGE()                                         \
  do {                                                  \
    gload16(kp0, &Ks[0][w * 512]);                      \
    gload16(kp0 + 2048, &Ks[0][2048 + w * 512]);        \
    gload16(kp1, &Ks[1][w * 512]);                      \
    gload16(kp1 + 2048, &Ks[1][2048 + w * 512]);        \
    gload16(vp0, &Vs[0][w * 512]);                      \
    gload16(vp0 + 32 * S, &Vs[0][2048 + w * 512]);      \
    gload16(vp1, &Vs[1][w * 512]);                      \
    gload16(vp1 + 32 * S, &Vs[1][2048 + w * 512]);      \
    kp0 += 4096; kp1 += 4096; vp0 += 64; vp1 += 64;     \
  } while (0)

#define LOADB(BC, MC)                                \
  do {                                               \
    BC[0] = *(const f32x4*)(bp);                     \
    BC[1] = *(const f32x4*)(bp + 16);                \
    BC[2] = *(const f32x4*)(bp + 32);                \
    BC[3] = *(const f32x4*)(bp + 48);                \
    MC[0][0] = *(const uint32_t*)(mp0);              \
    MC[0][1] = *(const uint32_t*)(mp0 + 16);         \
    MC[0][2] = *(const uint32_t*)(mp0 + 32);         \
    MC[0][3] = *(const uint32_t*)(mp0 + 48);         \
    MC[1][0] = *(const uint32_t*)(mp1);              \
    MC[1][1] = *(const uint32_t*)(mp1 + 16);         \
    MC[1][2] = *(const uint32_t*)(mp1 + 32);         \
    MC[1][3] = *(const uint32_t*)(mp1 + 48);         \
    bp += 64; mp0 += 64; mp1 += 64;                  \
  } while (0)

#define COMPUTE(BC, MC)                                                                  \
  do {                                                                                   \
    f32x4 sacc[2][4];                                                                    \
    _Pragma("unroll") for (int bb = 0; bb < 2; ++bb)                                     \
      _Pragma("unroll") for (int n = 0; n < 4; ++n) {                                    \
        const f16x8 kf0 = *swzr(&Ks[bb][0], n * 16 + l15, l4 * 16);                      \
        sacc[bb][n] = __builtin_amdgcn_mfma_f32_16x16x32_f16(                            \
            kf0, qf[bb][0], BC[n], 0, 0, 0); /* C-init = raw bias frag */                \
        const f16x8 kf1 = *swzr(&Ks[bb][0], n * 16 + l15, 64 + l4 * 16);                 \
        sacc[bb][n] = __builtin_amdgcn_mfma_f32_16x16x32_f16(                            \
            kf1, qf[bb][1], sacc[bb][n], 0, 0, 0);                                       \
      }                                                                                  \
    _Pragma("unroll") for (int bb = 0; bb < 2; ++bb) {                                   \
      float tmax = -3e38f;                                                               \
      _Pragma("unroll") for (int n = 0; n < 4; ++n) {                                    \
        _Pragma("unroll") for (int j = 0; j < 4; ++j) {                                  \
          const float mf = (float)((MC[bb][n] >> (8 * j)) & 255u);                       \
          sacc[bb][n][j] = fmaf(mf, -2e9f, sacc[bb][n][j]);                              \
        }                                                                                \
        tmax = fmaxf(tmax, fmaxf(fmaxf(sacc[bb][n][0], sacc[bb][n][1]),                  \
                                 fmaxf(sacc[bb][n][2], sacc[bb][n][3])));                \
      }                                                                                  \
      tmax = fmaxf(tmax, __shfl_xor(tmax, 16));                                          \
      tmax = fmaxf(tmax, __shfl_xor(tmax, 32));                                          \
      const float mnew = fmaxf(mrow[bb], tmax);                                          \
      const float negmL = -mnew * LOG2E;                                                 \
      const float alpha = __builtin_exp2f(fmaf(mrow[bb], LOG2E, negmL));                 \
      mrow[bb] = mnew;                                                                   \
      float lsum = 0.f;                                                                  \
      _Pragma("unroll") for (int n = 0; n < 4; ++n)                                      \
        _Pragma("unroll") for (int j = 0; j < 4; ++j) {                                  \
          const float e = __builtin_exp2f(fmaf(sacc[bb][n][j], LOG2E, negmL));           \
          sacc[bb][n][j] = e;                                                            \
          lsum += e;                                                                     \
        }                                                                                \
      lsum += __shfl_xor(lsum, 16);                                                      \
      lsum += __shfl_xor(lsum, 32);                                                      \
      lrow[bb] = lrow[bb] * alpha + lsum;                                                \
      float aq[4];                                                                       \
      _Pragma("unroll") for (int j = 0; j < 4; ++j) aq[j] = __shfl(alpha, l4 * 4 + j);   \
      _Pragma("unroll") for (int n = 0; n < 4; ++n)                                      \
        _Pragma("unroll") for (int j = 0; j < 4; ++j) oacc[bb][n][j] *= aq[j];           \
      _Pragma("unroll") for (int n = 0; n < 4; ++n) {                                    \
        const h2 p01 = __builtin_amdgcn_cvt_pkrtz(sacc[bb][n][0], sacc[bb][n][1]);       \
        const h2 p23 = __builtin_amdgcn_cvt_pkrtz(sacc[bb][n][2], sacc[bb][n][3]);       \
        uint2 pk;                                                                        \
        pk.x = __builtin_bit_cast(unsigned int, p01);                                    \
        pk.y = __builtin_bit_cast(unsigned int, p23);                                    \
        *(uint2*)((char*)&Ps[w][0] + l15 * 128 +                                         \
                  ((32 * n + 8 * l4) ^ ((l15 & 7) << 4))) = pk;                          \
      }                                                                                  \
      f16x8 pf[2];                                                                       \
      _Pragma("unroll") for (int ks = 0; ks < 2; ++ks)                                   \
        pf[ks] = *swzr(&Ps[w][0], l15, ks * 64 + l4 * 16);                               \
      _Pragma("unroll") for (int ks = 0; ks < 2; ++ks)                                   \
        _Pragma("unroll") for (int n = 0; n < 4; ++n) {                                  \
          const f16x8 vf = *swzr(&Vs[bb][0], n * 16 + l15, ks * 64 + l4 * 16);           \
          oacc[bb][n] = __builtin_amdgcn_mfma_f32_16x16x32_f16(pf[ks], vf,               \
                                                               oacc[bb][n], 0, 0, 0);    \
        }                                                                                \
    }                                                                                    \
  } while (0)

  STAGE();        // tile 0
  LOADB(bcA, mcA);
  __syncthreads();

#pragma unroll 1
  for (int it = 0; it < 8; ++it) {
    LOADB(bcB, mcB);          // tile 2it+1 bias/mask (full tile of flight)
    COMPUTE(bcA, mcA);        // tile 2it
    __syncthreads();          // K/V buffer free
    STAGE();                  // tile 2it+1
    __syncthreads();
    if (it < 7) LOADB(bcA, mcA);  // tile 2it+2
    COMPUTE(bcB, mcB);        // tile 2it+1
    __syncthreads();
    if (it < 7) STAGE();      // tile 2it+2
    __syncthreads();
  }
#undef COMPUTE
#undef LOADB
#undef STAGE

  // ---- store partials: O/l (f16), m, l ----
#pragma unroll
  for (int bb = 0; bb < 2; ++bb) {
    const size_t rowb = ((size_t)((half * 2 + bb) * 16 + h)) * 2048;
    const float inv = 1.0f / lrow[bb];
    float invq[4];
#pragma unroll
    for (int j = 0; j < 4; ++j) invq[j] = __shfl(inv, l4 * 4 + j);
#pragma unroll
    for (int j = 0; j < 4; ++j) {
      const int qrow = q0 + l4 * 4 + j;
#pragma unroll
      for (int n = 0; n < 4; ++n)
        Op[(rowb + qrow) * 64 + n * 16 + l15] = (f16)(oacc[bb][n][j] * invq[j]);
    }
    if (l4 == 0) {
      mArr[rowb + q0 + l15] = mrow[bb];
      lArr[rowb + q0 + l15] = lrow[bb];
    }
  }
}

// ---------------- split-K combine -----------------------------------------
// X[bb][q][h*64+d] = (w0*O0n + w1*O1n)/(w0+w1), w_i = exp(m_i - M)*l_i.
__global__ __launch_bounds__(256) void attn_combine(
    const f16* __restrict__ Op, const float* __restrict__ mArr,
    const float* __restrict__ lArr, f16* __restrict__ X) {
  const int e8 = blockIdx.x * 256 + threadIdx.x;  // 0 .. 524287
  const int d0 = (e8 & 7) * 8;
  const int q = (e8 >> 3) & 2047;
  const int h = (e8 >> 14) & 15;
  const int bb = e8 >> 18;
  const size_t row = (size_t)(bb * 16 + h) * 2048 + q;
  const size_t hs_ml = (size_t)65536;          // half stride in m/l
  const size_t hs_o = (size_t)65536 * 64;      // half stride in Op
  const float m0 = mArr[row], m1 = mArr[hs_ml + row];
  const float l0 = lArr[row], l1 = lArr[hs_ml + row];
  const float M = fmaxf(m0, m1);
  const float w0 = __builtin_exp2f((m0 - M) * LOG2E) * l0;
  const float w1 = __builtin_exp2f((m1 - M) * LOG2E) * l1;
  const float inv = 1.0f / (w0 + w1);
  const float a0 = w0 * inv, a1 = w1 * inv;
  const f16x8 o0 = *(const f16x8*)(Op + row * 64 + d0);
  const f16x8 o1 = *(const f16x8*)(Op + hs_o + row * 64 + d0);
  f16x8 o;
#pragma unroll
  for (int j = 0; j < 8; ++j)
    o[j] = (f16)(a0 * (float)o0[j] + a1 * (float)o1[j]);
  *(f16x8*)(X + (size_t)(bb * 2048 + q) * 1024 + h * 64 + d0) = o;
}

// ---------------- host ------------------------------------------------------
extern "C" void kernel_launch(void* const* d_in, const int* in_sizes, int n_in,
                              void* d_out, int out_size, void* d_ws, size_t ws_size,
                              hipStream_t stream) {
  const float* query = (const float*)d_in[0];
  const float* key_ = (const float*)d_in[1];
  const float* value = (const float*)d_in[2];
  const uint8_t* mask = (const uint8_t*)d_in[3];
  const float* bias = (const float*)d_in[4];
  const float* Wq = (const float*)d_in[5];
  const float* bq = (const float*)d_in[6];
  const float* Wk = (const float*)d_in[7];
  const float* bk = (const float*)d_in[8];
  const float* Wv = (const float*)d_in[9];
  const float* bv = (const float*)d_in[10];
  const float* Wo = (const float*)d_in[11];
  const float* bo = (const float*)d_in[12];

  char* p = (char*)d_ws;
  f16* qh = (f16*)p; p += (size_t)4194304 * 2;   // contiguous cvt dst region:
  f16* kh = (f16*)p; p += (size_t)4194304 * 2;   // qh,kh,vh,wqh,wkh,wvh,woh
  f16* vh = (f16*)p; p += (size_t)4194304 * 2;
  f16* wqh = (f16*)p; p += (size_t)1048576 * 2;
  f16* wkh = (f16*)p; p += (size_t)1048576 * 2;
  f16* wvh = (f16*)p; p += (size_t)1048576 * 2;
  f16* woh = (f16*)p; p += (size_t)1048576 * 2;
  f16* Qp = (f16*)p; p += (size_t)4194304 * 2;
  f16* Kp = (f16*)p; p += (size_t)4194304 * 2;
  f16* Vt = (f16*)p; p += (size_t)4194304 * 2;
  f16* Xh = (f16*)p; p += (size_t)4194304 * 2;
  f16* Opart = (f16*)p; p += (size_t)8388608 * 2;   // [2][2][16][2048][64]
  float* mArr = (float*)p; p += (size_t)131072 * 4; // [2][2][16][2048]
  float* lArr = (float*)p; p += (size_t)131072 * 4;
  uint8_t* m8 = (uint8_t*)p; p += (size_t)8388608;
  int* flag = (int*)p; p += 256;
  if (ws_size < (size_t)(p - (char*)d_ws)) return;

  mask_detect<<<1, 256, 0, stream>>>(mask, flag);
  mask_canon<<<8192, 256, 0, stream>>>(mask, m8, flag);

  CvtSrcs cs;
  cs.s[0] = query; cs.s[1] = key_; cs.s[2] = value;
  cs.s[3] = Wq; cs.s[4] = Wk; cs.s[5] = Wv; cs.s[6] = Wo;
  cvt_all<<<16384, 256, 0, stream>>>(cs, qh);

  gemm_qkv<<<1536, 256, 0, stream>>>(qh, kh, vh, wqh, wkh, wvh, bq, bk, bv,
                                     Qp, Kp, Vt);

  attn_fwd<<<1024, 256, 0, stream>>>(Qp, Kp, Vt, bias, m8, Opart, mArr, lArr);
  attn_combine<<<2048, 256, 0, stream>>>(Opart, mArr, lArr, Xh);

  gemm_out<<<512, 256, 0, stream>>>(Xh, woh, bo, (float*)d_out);
}

// Round 12
// 392.461 us; speedup vs baseline: 1.1982x; 1.1982x over previous
//
#include <hip/hip_runtime.h>
#include <stdint.h>

// MultiHeadedAttention: B=2,S=2048,D=1024,H=16,DK=64
// Pipeline: fused f32->f16 cvt; fused QKV proj GEMM (MFMA f16, Q scaled
// 0.125); SPLIT-K batch-merged flash attention (grid 1024 = qt x h x
// kv-half; launch_bounds(256,3) -> ~170 reg budget, NO SPILL; bias as MFMA
// C-operand; partials f16 + m/l f32); combine kernel; out proj GEMM -> f32.

typedef _Float16 f16;
typedef _Float16 f16x8 __attribute__((ext_vector_type(8)));
typedef _Float16 f16x4 __attribute__((ext_vector_type(4)));
typedef __fp16 h2 __attribute__((ext_vector_type(2)));
typedef float f32x4 __attribute__((ext_vector_type(4)));

#define LOG2E 1.44269504088896340736f

__device__ __forceinline__ void gload16(const void* g, void* l) {
  __builtin_amdgcn_global_load_lds(
      (const __attribute__((address_space(1))) unsigned int*)g,
      (__attribute__((address_space(3))) unsigned int*)l, 16, 0, 0);
}

// ---------------- fused f32 -> f16 conversion ------------------------------
struct CvtSrcs { const float* s[7]; };

__global__ __launch_bounds__(256) void cvt_all(CvtSrcs a, f16* __restrict__ out) {
  const int i = blockIdx.x * 256 + threadIdx.x;  // 0 .. 4194303
  int r, base;
  if (i < 3145728) { r = i >> 20; base = r << 20; }
  else { r = 3 + ((i - 3145728) >> 18); base = 3145728 + ((r - 3) << 18); }
  const float4 v = ((const float4*)a.s[r])[i - base];
  f16x4 o = {(f16)v.x, (f16)v.y, (f16)v.z, (f16)v.w};
  ((f16x4*)out)[i] = o;
}

// ---------------- mask dtype classify + canonicalize to u8 ----------------
__global__ void mask_detect(const uint8_t* __restrict__ m, int* __restrict__ flag) {
  __shared__ int s_off, s_weird;
  const int t = threadIdx.x;
  if (t == 0) { s_off = 0; s_weird = 0; }
  __syncthreads();
  int f_off = 0, f_weird = 0;
  for (int i = t; i < 8192; i += 256) {
    const uint8_t v = m[i];
    if ((i & 3) && v) f_off = 1;
    if (v > 1) f_weird = 1;
  }
  if (f_off) atomicOr(&s_off, 1);
  if (f_weird) atomicOr(&s_weird, 1);
  __syncthreads();
  if (t == 0) *flag = (s_off && !s_weird) ? 1 : 0;  // 1 => byte-sized bool
}

__global__ __launch_bounds__(256) void mask_canon(const uint8_t* __restrict__ m,
                                                  uint8_t* __restrict__ out,
                                                  const int* __restrict__ flag) {
  const int i = (blockIdx.x * 256 + threadIdx.x) * 4;  // grid covers 8388608
  uchar4 o;
  if (*flag) {
    const uchar4 v = *(const uchar4*)(m + i);
    o = make_uchar4(v.x != 0, v.y != 0, v.z != 0, v.w != 0);
  } else {
    const int4 v = *(const int4*)((const int*)m + i);
    o = make_uchar4(v.x != 0, v.y != 0, v.z != 0, v.w != 0);
  }
  *(uchar4*)(out + i) = o;
}

// ---------------- fused QKV projection GEMM --------------------------------
__global__ __launch_bounds__(256, 2) void gemm_qkv(
    const f16* __restrict__ qh, const f16* __restrict__ kh, const f16* __restrict__ vh,
    const f16* __restrict__ wq, const f16* __restrict__ wk, const f16* __restrict__ wv,
    const float* __restrict__ bq, const float* __restrict__ bk, const float* __restrict__ bv,
    f16* __restrict__ Qp, f16* __restrict__ Kp, f16* __restrict__ Vt) {
  constexpr int K = 1024;
  const int t = threadIdx.x;
  const int w = t >> 6, lane = t & 63, l15 = lane & 15, l4 = lane >> 4;
  const int nt = (int)blockIdx.x % 48;
  const int bm = ((int)blockIdx.x / 48) * 128;
  const int which = nt >> 4;
  const int bn = (nt & 15) * 64;
  const f16* A = which == 0 ? qh : which == 1 ? kh : vh;
  const f16* Bw = which == 0 ? wq : which == 1 ? wk : wv;
  const float* bias = which == 0 ? bq : which == 1 ? bk : bv;

  __shared__ f16 As[2][128 * 32];
  __shared__ f16 Bs[2][64 * 32];

  const f16* a0 = A + (size_t)(bm + (t >> 2)) * K + (t & 3) * 8;
  const f16* a1 = a0 + (size_t)64 * K;
  const f16* b0 = Bw + (size_t)(bn + (t >> 2)) * K + (t & 3) * 8;

  f32x4 acc[2][4];
#pragma unroll
  for (int m = 0; m < 2; ++m)
#pragma unroll
    for (int n = 0; n < 4; ++n) acc[m][n] = (f32x4){0.f, 0.f, 0.f, 0.f};

#define STAGE_G(buf, k0)                          \
  do {                                            \
    gload16(a0 + (k0), &As[buf][w * 512]);        \
    gload16(a1 + (k0), &As[buf][2048 + w * 512]); \
    gload16(b0 + (k0), &Bs[buf][w * 512]);        \
  } while (0)

  STAGE_G(0, 0);
  __syncthreads();
  int cur = 0;
#pragma unroll 1
  for (int kt = 0; kt < 32; ++kt) {
    if (kt < 31) STAGE_G(cur ^ 1, (kt + 1) * 32);
    const f16* ap = &As[cur][(w * 32 + l15) * 32 + l4 * 8];
    const f16* bp = &Bs[cur][l15 * 32 + l4 * 8];
    f16x8 af[2], bfr[4];
#pragma unroll
    for (int m = 0; m < 2; ++m) af[m] = *(const f16x8*)(ap + m * 512);
#pragma unroll
    for (int n = 0; n < 4; ++n) bfr[n] = *(const f16x8*)(bp + n * 512);
#pragma unroll
    for (int m = 0; m < 2; ++m)
#pragma unroll
      for (int n = 0; n < 4; ++n)
        acc[m][n] = __builtin_amdgcn_mfma_f32_16x16x32_f16(af[m], bfr[n], acc[m][n], 0, 0, 0);
    __syncthreads();
    cur ^= 1;
  }
#undef STAGE_G

  const float scale = which == 0 ? 0.125f : 1.0f;
  f16* outp = which == 0 ? Qp : which == 1 ? Kp : Vt;
#pragma unroll
  for (int m = 0; m < 2; ++m) {
    const int r0 = bm + w * 32 + m * 16 + (l4 << 2);
#pragma unroll
    for (int n = 0; n < 4; ++n) {
      const int c = bn + n * 16 + l15;
      const float bv = bias[c];
#pragma unroll
      for (int j = 0; j < 4; ++j) {
        const int r = r0 + j;
        const float v = (acc[m][n][j] + bv) * scale;
        const int b_ = r >> 11, s = r & 2047, h_ = c >> 6, dk = c & 63;
        if (which < 2)
          outp[(((size_t)b_ * 16 + h_) * 2048 + s) * 64 + dk] = (f16)v;
        else
          outp[(((size_t)b_ * 16 + h_) * 64 + dk) * 2048 + s] = (f16)v;
      }
    }
  }
}

// ---------------- output projection GEMM (f32 out) -------------------------
__global__ __launch_bounds__(256, 2) void gemm_out(const f16* __restrict__ A,
                                                   const f16* __restrict__ Bw,
                                                   const float* __restrict__ bias,
                                                   float* __restrict__ outp) {
  constexpr int K = 1024;
  const int t = threadIdx.x;
  const int w = t >> 6, lane = t & 63, l15 = lane & 15, l4 = lane >> 4;
  const int bm = (int)(blockIdx.x >> 4) * 128;
  const int bn = (int)(blockIdx.x & 15) * 64;

  __shared__ f16 As[2][128 * 32];
  __shared__ f16 Bs[2][64 * 32];

  const f16* a0 = A + (size_t)(bm + (t >> 2)) * K + (t & 3) * 8;
  const f16* a1 = a0 + (size_t)64 * K;
  const f16* b0 = Bw + (size_t)(bn + (t >> 2)) * K + (t & 3) * 8;

  f32x4 acc[2][4];
#pragma unroll
  for (int m = 0; m < 2; ++m)
#pragma unroll
    for (int n = 0; n < 4; ++n) acc[m][n] = (f32x4){0.f, 0.f, 0.f, 0.f};

#define STAGE_G(buf, k0)                          \
  do {                                            \
    gload16(a0 + (k0), &As[buf][w * 512]);        \
    gload16(a1 + (k0), &As[buf][2048 + w * 512]); \
    gload16(b0 + (k0), &Bs[buf][w * 512]);        \
  } while (0)

  STAGE_G(0, 0);
  __syncthreads();
  int cur = 0;
#pragma unroll 1
  for (int kt = 0; kt < 32; ++kt) {
    if (kt < 31) STAGE_G(cur ^ 1, (kt + 1) * 32);
    const f16* ap = &As[cur][(w * 32 + l15) * 32 + l4 * 8];
    const f16* bp = &Bs[cur][l15 * 32 + l4 * 8];
    f16x8 af[2], bfr[4];
#pragma unroll
    for (int m = 0; m < 2; ++m) af[m] = *(const f16x8*)(ap + m * 512);
#pragma unroll
    for (int n = 0; n < 4; ++n) bfr[n] = *(const f16x8*)(bp + n * 512);
#pragma unroll
    for (int m = 0; m < 2; ++m)
#pragma unroll
      for (int n = 0; n < 4; ++n)
        acc[m][n] = __builtin_amdgcn_mfma_f32_16x16x32_f16(af[m], bfr[n], acc[m][n], 0, 0, 0);
    __syncthreads();
    cur ^= 1;
  }
#undef STAGE_G

#pragma unroll
  for (int m = 0; m < 2; ++m) {
    const int r0 = bm + w * 32 + m * 16 + (l4 << 2);
#pragma unroll
    for (int n = 0; n < 4; ++n) {
      const int c = bn + n * 16 + l15;
      const float bv = bias[c];
#pragma unroll
      for (int j = 0; j < 4; ++j)
        outp[(size_t)(r0 + j) * 1024 + c] = acc[m][n][j] + bv;
    }
  }
}

// ---------------- split-K batch-merged flash attention ---------------------
// 1024 blocks: bid -> (qt 0..31, h 0..15, half 0..1). Each block: 64 q-rows,
// both batches, kv in [half*1024, half*1024+1024) as 16 tiles of 64.
// launch_bounds(256,3): ~170-reg budget fits the ~150-reg live state (the
// (256,4)=128-reg cap caused 468MB of spill traffic in R11). 3 blocks/CU.
__device__ __forceinline__ const f16x8* swzr(const f16* base, int row, int bytecol) {
  return (const f16x8*)((const char*)base + row * 128 + (bytecol ^ ((row & 7) << 4)));
}

__global__ __launch_bounds__(256, 3) void attn_fwd(
    const f16* __restrict__ Qp, const f16* __restrict__ Kp,
    const f16* __restrict__ Vt, const float* __restrict__ bias,
    const uint8_t* __restrict__ mask, f16* __restrict__ Op,
    float* __restrict__ mArr, float* __restrict__ lArr) {
  constexpr int S = 2048;
  const int bid = blockIdx.x;
  const int half = bid >> 9;
  const int qt = bid & 31, h = (bid >> 5) & 15;
  const int t = threadIdx.x, w = t >> 6, lane = t & 63;
  const int l15 = lane & 15, l4 = lane >> 4;
  const int q0 = qt * 64 + w * 16;
  const int k0g = half * 1024;

  const f16* Qb0 = Qp + (size_t)h * S * 64;
  const f16* Qb1 = Qp + (size_t)(16 + h) * S * 64;

  __shared__ f16 Ks[2][64 * 64];  // [batch][kv][dk], swizzled (single buf)
  __shared__ f16 Vs[2][64 * 64];  // [batch][dk][kv], swizzled
  __shared__ f16 Ps[4][16 * 64];  // per-wave P, swizzled

  f16x8 qf[2][2];
#pragma unroll
  for (int ks = 0; ks < 2; ++ks) {
    qf[0][ks] = *(const f16x8*)(Qb0 + (size_t)(q0 + l15) * 64 + ks * 32 + l4 * 8);
    qf[1][ks] = *(const f16x8*)(Qb1 + (size_t)(q0 + l15) * 64 + ks * 32 + l4 * 8);
  }

  f32x4 oacc[2][4];
#pragma unroll
  for (int bb = 0; bb < 2; ++bb)
#pragma unroll
    for (int n = 0; n < 4; ++n) oacc[bb][n] = (f32x4){0.f, 0.f, 0.f, 0.f};
  float mrow[2] = {-3e38f, -3e38f}, lrow[2] = {0.f, 0.f};

  // running source pointers (pre-offset by kv half)
  const int srow = t >> 3;
  const int scol = (((t & 7) ^ (srow & 7)) << 3);
  const f16* kp0 = Kp + (size_t)h * S * 64 + (size_t)(k0g + srow) * 64 + scol;
  const f16* kp1 = kp0 + (size_t)16 * S * 64;
  const f16* vp0 = Vt + (size_t)h * 64 * S + (size_t)srow * S + k0g + scol;
  const f16* vp1 = vp0 + (size_t)16 * 64 * S;
  const float* bp = bias + (size_t)h * S * S + (size_t)(q0 + l15) * S + k0g + l4 * 4;
  const uint8_t* mp0 = mask + (size_t)(q0 + l15) * S + k0g + l4 * 4;
  const uint8_t* mp1 = mp0 + (size_t)S * S;

  f32x4 bcA[4], bcB[4];
  uint32_t mcA[2][4], mcB[2][4];

#define STAGE()                                         \
  do {                                                  \
    gload16(kp0, &Ks[0][w * 512]);                      \
    gload16(kp0 + 2048, &Ks[0][2048 + w * 512]);        \
    gload16(kp1, &Ks[1][w * 512]);                      \
    gload16(kp1 + 2048, &Ks[1][2048 + w * 512]);        \
    gload16(vp0, &Vs[0][w * 512]);                      \
    gload16(vp0 + 32 * S, &Vs[0][2048 + w * 512]);      \
    gload16(vp1, &Vs[1][w * 512]);                      \
    gload16(vp1 + 32 * S, &Vs[1][2048 + w * 512]);      \
    kp0 += 4096; kp1 += 4096; vp0 += 64; vp1 += 64;     \
  } while (0)

#define LOADB(BC, MC)                                \
  do {                                               \
    BC[0] = *(const f32x4*)(bp);                     \
    BC[1] = *(const f32x4*)(bp + 16);                \
    BC[2] = *(const f32x4*)(bp + 32);                \
    BC[3] = *(const f32x4*)(bp + 48);                \
    MC[0][0] = *(const uint32_t*)(mp0);              \
    MC[0][1] = *(const uint32_t*)(mp0 + 16);         \
    MC[0][2] = *(const uint32_t*)(mp0 + 32);         \
    MC[0][3] = *(const uint32_t*)(mp0 + 48);         \
    MC[1][0] = *(const uint32_t*)(mp1);              \
    MC[1][1] = *(const uint32_t*)(mp1 + 16);         \
    MC[1][2] = *(const uint32_t*)(mp1 + 32);         \
    MC[1][3] = *(const uint32_t*)(mp1 + 48);         \
    bp += 64; mp0 += 64; mp1 += 64;                  \
  } while (0)

#define COMPUTE(BC, MC)                                                                  \
  do {                                                                                   \
    f32x4 sacc[2][4];                                                                    \
    _Pragma("unroll") for (int bb = 0; bb < 2; ++bb)                                     \
      _Pragma("unroll") for (int n = 0; n < 4; ++n) {                                    \
        const f16x8 kf0 = *swzr(&Ks[bb][0], n * 16 + l15, l4 * 16);                      \
        sacc[bb][n] = __builtin_amdgcn_mfma_f32_16x16x32_f16(                            \
            kf0, qf[bb][0], BC[n], 0, 0, 0); /* C-init = raw bias frag */                \
        const f16x8 kf1 = *swzr(&Ks[bb][0], n * 16 + l15, 64 + l4 * 16);                 \
        sacc[bb][n] = __builtin_amdgcn_mfma_f32_16x16x32_f16(                            \
            kf1, qf[bb][1], sacc[bb][n], 0, 0, 0);                                       \
      }                                                                                  \
    _Pragma("unroll") for (int bb = 0; bb < 2; ++bb) {                                   \
      float tmax = -3e38f;                                                               \
      _Pragma("unroll") for (int n = 0; n < 4; ++n) {                                    \
        _Pragma("unroll") for (int j = 0; j < 4; ++j) {                                  \
          const float mf = (float)((MC[bb][n] >> (8 * j)) & 255u);                       \
          sacc[bb][n][j] = fmaf(mf, -2e9f, sacc[bb][n][j]);                              \
        }                                                                                \
        tmax = fmaxf(tmax, fmaxf(fmaxf(sacc[bb][n][0], sacc[bb][n][1]),                  \
                                 fmaxf(sacc[bb][n][2], sacc[bb][n][3])));                \
      }                                                                                  \
      tmax = fmaxf(tmax, __shfl_xor(tmax, 16));                                          \
      tmax = fmaxf(tmax, __shfl_xor(tmax, 32));                                          \
      const float mnew = fmaxf(mrow[bb], tmax);                                          \
      const float negmL = -mnew * LOG2E;                                                 \
      const float alpha = __builtin_exp2f(fmaf(mrow[bb], LOG2E, negmL));                 \
      mrow[bb] = mnew;                                                                   \
      float lsum = 0.f;                                                                  \
      _Pragma("unroll") for (int n = 0; n < 4; ++n)                                      \
        _Pragma("unroll") for (int j = 0; j < 4; ++j) {                                  \
          const float e = __builtin_exp2f(fmaf(sacc[bb][n][j], LOG2E, negmL));           \
          sacc[bb][n][j] = e;                                                            \
          lsum += e;                                                                     \
        }                                                                                \
      lsum += __shfl_xor(lsum, 16);                                                      \
      lsum += __shfl_xor(lsum, 32);                                                      \
      lrow[bb] = lrow[bb] * alpha + lsum;                                                \
      float aq[4];                                                                       \
      _Pragma("unroll") for (int j = 0; j < 4; ++j) aq[j] = __shfl(alpha, l4 * 4 + j);   \
      _Pragma("unroll") for (int n = 0; n < 4; ++n)                                      \
        _Pragma("unroll") for (int j = 0; j < 4; ++j) oacc[bb][n][j] *= aq[j];           \
      _Pragma("unroll") for (int n = 0; n < 4; ++n) {                                    \
        const h2 p01 = __builtin_amdgcn_cvt_pkrtz(sacc[bb][n][0], sacc[bb][n][1]);       \
        const h2 p23 = __builtin_amdgcn_cvt_pkrtz(sacc[bb][n][2], sacc[bb][n][3]);       \
        uint2 pk;                                                                        \
        pk.x = __builtin_bit_cast(unsigned int, p01);                                    \
        pk.y = __builtin_bit_cast(unsigned int, p23);                                    \
        *(uint2*)((char*)&Ps[w][0] + l15 * 128 +                                         \
                  ((32 * n + 8 * l4) ^ ((l15 & 7) << 4))) = pk;                          \
      }                                                                                  \
      f16x8 pf[2];                                                                       \
      _Pragma("unroll") for (int ks = 0; ks < 2; ++ks)                                   \
        pf[ks] = *swzr(&Ps[w][0], l15, ks * 64 + l4 * 16);                               \
      _Pragma("unroll") for (int ks = 0; ks < 2; ++ks)                                   \
        _Pragma("unroll") for (int n = 0; n < 4; ++n) {                                  \
          const f16x8 vf = *swzr(&Vs[bb][0], n * 16 + l15, ks * 64 + l4 * 16);           \
          oacc[bb][n] = __builtin_amdgcn_mfma_f32_16x16x32_f16(pf[ks], vf,               \
                                                               oacc[bb][n], 0, 0, 0);    \
        }                                                                                \
    }                                                                                    \
  } while (0)

  STAGE();        // tile 0
  LOADB(bcA, mcA);
  __syncthreads();

#pragma unroll 1
  for (int it = 0; it < 8; ++it) {
    LOADB(bcB, mcB);          // tile 2it+1 bias/mask (full tile of flight)
    COMPUTE(bcA, mcA);        // tile 2it
    __syncthreads();          // K/V buffer free
    STAGE();                  // tile 2it+1
    __syncthreads();
    if (it < 7) LOADB(bcA, mcA);  // tile 2it+2
    COMPUTE(bcB, mcB);        // tile 2it+1
    __syncthreads();
    if (it < 7) STAGE();      // tile 2it+2
    __syncthreads();
  }
#undef COMPUTE
#undef LOADB
#undef STAGE

  // ---- store partials: O/l (f16), m, l ----
#pragma unroll
  for (int bb = 0; bb < 2; ++bb) {
    const size_t rowb = ((size_t)((half * 2 + bb) * 16 + h)) * 2048;
    const float inv = 1.0f / lrow[bb];
    float invq[4];
#pragma unroll
    for (int j = 0; j < 4; ++j) invq[j] = __shfl(inv, l4 * 4 + j);
#pragma unroll
    for (int j = 0; j < 4; ++j) {
      const int qrow = q0 + l4 * 4 + j;
#pragma unroll
      for (int n = 0; n < 4; ++n)
        Op[(rowb + qrow) * 64 + n * 16 + l15] = (f16)(oacc[bb][n][j] * invq[j]);
    }
    if (l4 == 0) {
      mArr[rowb + q0 + l15] = mrow[bb];
      lArr[rowb + q0 + l15] = lrow[bb];
    }
  }
}

// ---------------- split-K combine -----------------------------------------
// X[bb][q][h*64+d] = (w0*O0n + w1*O1n)/(w0+w1), w_i = exp(m_i - M)*l_i.
__global__ __launch_bounds__(256) void attn_combine(
    const f16* __restrict__ Op, const float* __restrict__ mArr,
    const float* __restrict__ lArr, f16* __restrict__ X) {
  const int e8 = blockIdx.x * 256 + threadIdx.x;  // 0 .. 524287
  const int d0 = (e8 & 7) * 8;
  const int q = (e8 >> 3) & 2047;
  const int h = (e8 >> 14) & 15;
  const int bb = e8 >> 18;
  const size_t row = (size_t)(bb * 16 + h) * 2048 + q;
  const size_t hs_ml = (size_t)65536;          // half stride in m/l
  const size_t hs_o = (size_t)65536 * 64;      // half stride in Op
  const float m0 = mArr[row], m1 = mArr[hs_ml + row];
  const float l0 = lArr[row], l1 = lArr[hs_ml + row];
  const float M = fmaxf(m0, m1);
  const float w0 = __builtin_exp2f((m0 - M) * LOG2E) * l0;
  const float w1 = __builtin_exp2f((m1 - M) * LOG2E) * l1;
  const float inv = 1.0f / (w0 + w1);
  const float a0 = w0 * inv, a1 = w1 * inv;
  const f16x8 o0 = *(const f16x8*)(Op + row * 64 + d0);
  const f16x8 o1 = *(const f16x8*)(Op + hs_o + row * 64 + d0);
  f16x8 o;
#pragma unroll
  for (int j = 0; j < 8; ++j)
    o[j] = (f16)(a0 * (float)o0[j] + a1 * (float)o1[j]);
  *(f16x8*)(X + (size_t)(bb * 2048 + q) * 1024 + h * 64 + d0) = o;
}

// ---------------- host ------------------------------------------------------
extern "C" void kernel_launch(void* const* d_in, const int* in_sizes, int n_in,
                              void* d_out, int out_size, void* d_ws, size_t ws_size,
                              hipStream_t stream) {
  const float* query = (const float*)d_in[0];
  const float* key_ = (const float*)d_in[1];
  const float* value = (const float*)d_in[2];
  const uint8_t* mask = (const uint8_t*)d_in[3];
  const float* bias = (const float*)d_in[4];
  const float* Wq = (const float*)d_in[5];
  const float* bq = (const float*)d_in[6];
  const float* Wk = (const float*)d_in[7];
  const float* bk = (const float*)d_in[8];
  const float* Wv = (const float*)d_in[9];
  const float* bv = (const float*)d_in[10];
  const float* Wo = (const float*)d_in[11];
  const float* bo = (const float*)d_in[12];

  char* p = (char*)d_ws;
  f16* qh = (f16*)p; p += (size_t)4194304 * 2;   // contiguous cvt dst region:
  f16* kh = (f16*)p; p += (size_t)4194304 * 2;   // qh,kh,vh,wqh,wkh,wvh,woh
  f16* vh = (f16*)p; p += (size_t)4194304 * 2;
  f16* wqh = (f16*)p; p += (size_t)1048576 * 2;
  f16* wkh = (f16*)p; p += (size_t)1048576 * 2;
  f16* wvh = (f16*)p; p += (size_t)1048576 * 2;
  f16* woh = (f16*)p; p += (size_t)1048576 * 2;
  f16* Qp = (f16*)p; p += (size_t)4194304 * 2;
  f16* Kp = (f16*)p; p += (size_t)4194304 * 2;
  f16* Vt = (f16*)p; p += (size_t)4194304 * 2;
  f16* Xh = (f16*)p; p += (size_t)4194304 * 2;
  f16* Opart = (f16*)p; p += (size_t)8388608 * 2;   // [2][2][16][2048][64]
  float* mArr = (float*)p; p += (size_t)131072 * 4; // [2][2][16][2048]
  float* lArr = (float*)p; p += (size_t)131072 * 4;
  uint8_t* m8 = (uint8_t*)p; p += (size_t)8388608;
  int* flag = (int*)p; p += 256;
  if (ws_size < (size_t)(p - (char*)d_ws)) return;

  mask_detect<<<1, 256, 0, stream>>>(mask, flag);
  mask_canon<<<8192, 256, 0, stream>>>(mask, m8, flag);

  CvtSrcs cs;
  cs.s[0] = query; cs.s[1] = key_; cs.s[2] = value;
  cs.s[3] = Wq; cs.s[4] = Wk; cs.s[5] = Wv; cs.s[6] = Wo;
  cvt_all<<<16384, 256, 0, stream>>>(cs, qh);

  gemm_qkv<<<1536, 256, 0, stream>>>(qh, kh, vh, wqh, wkh, wvh, bq, bk, bv,
                                     Qp, Kp, Vt);

  attn_fwd<<<1024, 256, 0, stream>>>(Qp, Kp, Vt, bias, m8, Opart, mArr, lArr);
  attn_combine<<<2048, 256, 0, stream>>>(Opart, mArr, lArr, Xh);

  gemm_out<<<512, 256, 0, stream>>>(Xh, woh, bo, (float*)d_out);
}

// Round 13
// 263.522 us; speedup vs baseline: 1.7845x; 1.4893x over previous
//
#include <hip/hip_runtime.h>
#include <stdint.h>

// MultiHeadedAttention: B=2,S=2048,D=1024,H=16,DK=64
// Pipeline: fused f32->f16 cvt; fused QKV proj GEMM (MFMA f16, Q pre-scaled
// by 0.125*log2e); batch-merged flash attention (one block does b=0 AND b=1
// for a (h,q-tile): bias loaded once; T13 defer-max softmax); out proj.

typedef _Float16 f16;
typedef _Float16 f16x8 __attribute__((ext_vector_type(8)));
typedef _Float16 f16x4 __attribute__((ext_vector_type(4)));
typedef __fp16 h2 __attribute__((ext_vector_type(2)));
typedef float f32x4 __attribute__((ext_vector_type(4)));

#define LOG2E 1.44269504088896340736f

__device__ __forceinline__ void gload16(const void* g, void* l) {
  __builtin_amdgcn_global_load_lds(
      (const __attribute__((address_space(1))) unsigned int*)g,
      (__attribute__((address_space(3))) unsigned int*)l, 16, 0, 0);
}

// ---------------- fused f32 -> f16 conversion ------------------------------
struct CvtSrcs { const float* s[7]; };

__global__ __launch_bounds__(256) void cvt_all(CvtSrcs a, f16* __restrict__ out) {
  const int i = blockIdx.x * 256 + threadIdx.x;  // 0 .. 4194303
  int r, base;
  if (i < 3145728) { r = i >> 20; base = r << 20; }
  else { r = 3 + ((i - 3145728) >> 18); base = 3145728 + ((r - 3) << 18); }
  const float4 v = ((const float4*)a.s[r])[i - base];
  f16x4 o = {(f16)v.x, (f16)v.y, (f16)v.z, (f16)v.w};
  ((f16x4*)out)[i] = o;
}

// ---------------- mask dtype classify + canonicalize to u8 ----------------
__global__ void mask_detect(const uint8_t* __restrict__ m, int* __restrict__ flag) {
  __shared__ int s_off, s_weird;
  const int t = threadIdx.x;
  if (t == 0) { s_off = 0; s_weird = 0; }
  __syncthreads();
  int f_off = 0, f_weird = 0;
  for (int i = t; i < 8192; i += 256) {
    const uint8_t v = m[i];
    if ((i & 3) && v) f_off = 1;
    if (v > 1) f_weird = 1;
  }
  if (f_off) atomicOr(&s_off, 1);
  if (f_weird) atomicOr(&s_weird, 1);
  __syncthreads();
  if (t == 0) *flag = (s_off && !s_weird) ? 1 : 0;  // 1 => byte-sized bool
}

__global__ __launch_bounds__(256) void mask_canon(const uint8_t* __restrict__ m,
                                                  uint8_t* __restrict__ out,
                                                  const int* __restrict__ flag) {
  const int i = (blockIdx.x * 256 + threadIdx.x) * 4;  // grid covers 8388608
  uchar4 o;
  if (*flag) {
    const uchar4 v = *(const uchar4*)(m + i);
    o = make_uchar4(v.x != 0, v.y != 0, v.z != 0, v.w != 0);
  } else {
    const int4 v = *(const int4*)((const int*)m + i);
    o = make_uchar4(v.x != 0, v.y != 0, v.z != 0, v.w != 0);
  }
  *(uchar4*)(out + i) = o;
}

// ---------------- fused QKV projection GEMM --------------------------------
__global__ __launch_bounds__(256, 2) void gemm_qkv(
    const f16* __restrict__ qh, const f16* __restrict__ kh, const f16* __restrict__ vh,
    const f16* __restrict__ wq, const f16* __restrict__ wk, const f16* __restrict__ wv,
    const float* __restrict__ bq, const float* __restrict__ bk, const float* __restrict__ bv,
    f16* __restrict__ Qp, f16* __restrict__ Kp, f16* __restrict__ Vt) {
  constexpr int K = 1024;
  const int t = threadIdx.x;
  const int w = t >> 6, lane = t & 63, l15 = lane & 15, l4 = lane >> 4;
  const int nt = (int)blockIdx.x % 48;
  const int bm = ((int)blockIdx.x / 48) * 128;
  const int which = nt >> 4;
  const int bn = (nt & 15) * 64;
  const f16* A = which == 0 ? qh : which == 1 ? kh : vh;
  const f16* Bw = which == 0 ? wq : which == 1 ? wk : wv;
  const float* bias = which == 0 ? bq : which == 1 ? bk : bv;

  __shared__ f16 As[2][128 * 32];
  __shared__ f16 Bs[2][64 * 32];

  const f16* a0 = A + (size_t)(bm + (t >> 2)) * K + (t & 3) * 8;
  const f16* a1 = a0 + (size_t)64 * K;
  const f16* b0 = Bw + (size_t)(bn + (t >> 2)) * K + (t & 3) * 8;

  f32x4 acc[2][4];
#pragma unroll
  for (int m = 0; m < 2; ++m)
#pragma unroll
    for (int n = 0; n < 4; ++n) acc[m][n] = (f32x4){0.f, 0.f, 0.f, 0.f};

#define STAGE_G(buf, k0)                          \
  do {                                            \
    gload16(a0 + (k0), &As[buf][w * 512]);        \
    gload16(a1 + (k0), &As[buf][2048 + w * 512]); \
    gload16(b0 + (k0), &Bs[buf][w * 512]);        \
  } while (0)

  STAGE_G(0, 0);
  __syncthreads();
  int cur = 0;
#pragma unroll 1
  for (int kt = 0; kt < 32; ++kt) {
    if (kt < 31) STAGE_G(cur ^ 1, (kt + 1) * 32);
    const f16* ap = &As[cur][(w * 32 + l15) * 32 + l4 * 8];
    const f16* bp = &Bs[cur][l15 * 32 + l4 * 8];
    f16x8 af[2], bfr[4];
#pragma unroll
    for (int m = 0; m < 2; ++m) af[m] = *(const f16x8*)(ap + m * 512);
#pragma unroll
    for (int n = 0; n < 4; ++n) bfr[n] = *(const f16x8*)(bp + n * 512);
#pragma unroll
    for (int m = 0; m < 2; ++m)
#pragma unroll
      for (int n = 0; n < 4; ++n)
        acc[m][n] = __builtin_amdgcn_mfma_f32_16x16x32_f16(af[m], bfr[n], acc[m][n], 0, 0, 0);
    __syncthreads();
    cur ^= 1;
  }
#undef STAGE_G

  const float scale = which == 0 ? 0.125f * LOG2E : 1.0f;
  f16* outp = which == 0 ? Qp : which == 1 ? Kp : Vt;
#pragma unroll
  for (int m = 0; m < 2; ++m) {
    const int r0 = bm + w * 32 + m * 16 + (l4 << 2);
#pragma unroll
    for (int n = 0; n < 4; ++n) {
      const int c = bn + n * 16 + l15;
      const float bv = bias[c];
#pragma unroll
      for (int j = 0; j < 4; ++j) {
        const int r = r0 + j;
        const float v = (acc[m][n][j] + bv) * scale;
        const int b_ = r >> 11, s = r & 2047, h_ = c >> 6, dk = c & 63;
        if (which < 2)
          outp[(((size_t)b_ * 16 + h_) * 2048 + s) * 64 + dk] = (f16)v;
        else
          outp[(((size_t)b_ * 16 + h_) * 64 + dk) * 2048 + s] = (f16)v;
      }
    }
  }
}

// ---------------- output projection GEMM (f32 out) -------------------------
__global__ __launch_bounds__(256, 2) void gemm_out(const f16* __restrict__ A,
                                                   const f16* __restrict__ Bw,
                                                   const float* __restrict__ bias,
                                                   float* __restrict__ outp) {
  constexpr int K = 1024;
  const int t = threadIdx.x;
  const int w = t >> 6, lane = t & 63, l15 = lane & 15, l4 = lane >> 4;
  const int bm = (int)(blockIdx.x >> 4) * 128;
  const int bn = (int)(blockIdx.x & 15) * 64;

  __shared__ f16 As[2][128 * 32];
  __shared__ f16 Bs[2][64 * 32];

  const f16* a0 = A + (size_t)(bm + (t >> 2)) * K + (t & 3) * 8;
  const f16* a1 = a0 + (size_t)64 * K;
  const f16* b0 = Bw + (size_t)(bn + (t >> 2)) * K + (t & 3) * 8;

  f32x4 acc[2][4];
#pragma unroll
  for (int m = 0; m < 2; ++m)
#pragma unroll
    for (int n = 0; n < 4; ++n) acc[m][n] = (f32x4){0.f, 0.f, 0.f, 0.f};

#define STAGE_G(buf, k0)                          \
  do {                                            \
    gload16(a0 + (k0), &As[buf][w * 512]);        \
    gload16(a1 + (k0), &As[buf][2048 + w * 512]); \
    gload16(b0 + (k0), &Bs[buf][w * 512]);        \
  } while (0)

  STAGE_G(0, 0);
  __syncthreads();
  int cur = 0;
#pragma unroll 1
  for (int kt = 0; kt < 32; ++kt) {
    if (kt < 31) STAGE_G(cur ^ 1, (kt + 1) * 32);
    const f16* ap = &As[cur][(w * 32 + l15) * 32 + l4 * 8];
    const f16* bp = &Bs[cur][l15 * 32 + l4 * 8];
    f16x8 af[2], bfr[4];
#pragma unroll
    for (int m = 0; m < 2; ++m) af[m] = *(const f16x8*)(ap + m * 512);
#pragma unroll
    for (int n = 0; n < 4; ++n) bfr[n] = *(const f16x8*)(bp + n * 512);
#pragma unroll
    for (int m = 0; m < 2; ++m)
#pragma unroll
      for (int n = 0; n < 4; ++n)
        acc[m][n] = __builtin_amdgcn_mfma_f32_16x16x32_f16(af[m], bfr[n], acc[m][n], 0, 0, 0);
    __syncthreads();
    cur ^= 1;
  }
#undef STAGE_G

#pragma unroll
  for (int m = 0; m < 2; ++m) {
    const int r0 = bm + w * 32 + m * 16 + (l4 << 2);
#pragma unroll
    for (int n = 0; n < 4; ++n) {
      const int c = bn + n * 16 + l15;
      const float bv = bias[c];
#pragma unroll
      for (int j = 0; j < 4; ++j)
        outp[(size_t)(r0 + j) * 1024 + c] = acc[m][n][j] + bv;
    }
  }
}

// ---------------- batch-merged flash attention (R7 + T13) ------------------
// 512 blocks: bid -> (qt 0..31, h 0..15). Bias loaded once per tile, reused
// for both batches; K/V single-buffered LDS; swapped QK^T (lane owns q).
// T13 defer-max: rescale only when the tile max exceeds running max + 11.5
// (log2 units); P bounded by 2^11.5 (f16-safe). Tree tmax/lsum reductions.
__device__ __forceinline__ const f16x8* swzr(const f16* base, int row, int bytecol) {
  return (const f16x8*)((const char*)base + row * 128 + (bytecol ^ ((row & 7) << 4)));
}

__global__ __launch_bounds__(256, 2) void attn_fwd(
    const f16* __restrict__ Qp, const f16* __restrict__ Kp,
    const f16* __restrict__ Vt, const float* __restrict__ bias,
    const uint8_t* __restrict__ mask, f16* __restrict__ X) {
  constexpr int S = 2048;
  const int bid = blockIdx.x;
  const int qt = bid & 31, h = bid >> 5;
  const int t = threadIdx.x, w = t >> 6, lane = t & 63;
  const int l15 = lane & 15, l4 = lane >> 4;
  const int q0 = qt * 64 + w * 16;

  const f16* Qb[2] = {Qp + (size_t)h * S * 64, Qp + (size_t)(16 + h) * S * 64};
  const f16* Kb[2] = {Kp + (size_t)h * S * 64, Kp + (size_t)(16 + h) * S * 64};
  const f16* Vb[2] = {Vt + (size_t)h * 64 * S, Vt + (size_t)(16 + h) * 64 * S};
  const float* biasr = bias + (size_t)h * S * S + (size_t)(q0 + l15) * S + l4 * 4;
  const uint8_t* mr0 = mask + (size_t)(q0 + l15) * S + l4 * 4;
  const uint8_t* mr1 = mr0 + (size_t)S * S;

  __shared__ f16 Ks[2][64 * 64];  // [batch][kv][dk], swizzled
  __shared__ f16 Vs[2][64 * 64];  // [batch][dk][kv], swizzled
  __shared__ f16 Ps[4][16 * 64];  // per-wave P, swizzled (reused b0 then b1)

  // Q B-frags for both batches (Q pre-scaled by 0.125*log2e)
  f16x8 qf[2][2];
#pragma unroll
  for (int bb = 0; bb < 2; ++bb)
#pragma unroll
    for (int ks = 0; ks < 2; ++ks)
      qf[bb][ks] =
          *(const f16x8*)(Qb[bb] + (size_t)(q0 + l15) * 64 + ks * 32 + l4 * 8);

  f32x4 oacc[2][4];
#pragma unroll
  for (int bb = 0; bb < 2; ++bb)
#pragma unroll
    for (int n = 0; n < 4; ++n) oacc[bb][n] = (f32x4){0.f, 0.f, 0.f, 0.f};
  float mrow[2] = {-3e38f, -3e38f}, lrow[2] = {0.f, 0.f};

  const int srow = t >> 3;
  const int scol = (((t & 7) ^ (srow & 7)) << 3);

#define STAGE(kk)                                                                   \
  do {                                                                              \
    gload16(Kb[0] + (size_t)((kk) + srow) * 64 + scol, &Ks[0][w * 512]);            \
    gload16(Kb[0] + (size_t)((kk) + 32 + srow) * 64 + scol, &Ks[0][2048 + w * 512]);\
    gload16(Kb[1] + (size_t)((kk) + srow) * 64 + scol, &Ks[1][w * 512]);            \
    gload16(Kb[1] + (size_t)((kk) + 32 + srow) * 64 + scol, &Ks[1][2048 + w * 512]);\
    gload16(Vb[0] + (size_t)srow * S + (kk) + scol, &Vs[0][w * 512]);               \
    gload16(Vb[0] + (size_t)(32 + srow) * S + (kk) + scol, &Vs[0][2048 + w * 512]); \
    gload16(Vb[1] + (size_t)srow * S + (kk) + scol, &Vs[1][w * 512]);               \
    gload16(Vb[1] + (size_t)(32 + srow) * S + (kk) + scol, &Vs[1][2048 + w * 512]); \
  } while (0)

  STAGE(0);

#pragma unroll 1
  for (int kt = 0; kt < 32; ++kt) {
    const int k0 = kt * 64;
    // bias (shared by both batches) + masks — issued pre-barrier, drained by it
    f32x4 bc[4];
    uint32_t mc[2][4];
#pragma unroll
    for (int n = 0; n < 4; ++n) {
      bc[n] = *(const f32x4*)(biasr + k0 + n * 16);
      mc[0][n] = *(const uint32_t*)(mr0 + k0 + n * 16);
      mc[1][n] = *(const uint32_t*)(mr1 + k0 + n * 16);
    }
    __syncthreads();  // drains vmcnt: K/V tiles + bias/mask regs ready

    // ---- QK^T for both batches (swapped: lane owns q=q0+l15) ----
    f32x4 sacc[2][4];
#pragma unroll
    for (int bb = 0; bb < 2; ++bb)
#pragma unroll
      for (int n = 0; n < 4; ++n) sacc[bb][n] = (f32x4){0.f, 0.f, 0.f, 0.f};
#pragma unroll
    for (int bb = 0; bb < 2; ++bb)
#pragma unroll
      for (int n = 0; n < 4; ++n)
#pragma unroll
        for (int ks = 0; ks < 2; ++ks) {
          const f16x8 kf = *swzr(&Ks[bb][0], n * 16 + l15, ks * 64 + l4 * 16);
          sacc[bb][n] =
              __builtin_amdgcn_mfma_f32_16x16x32_f16(kf, qf[bb][ks], sacc[bb][n], 0, 0, 0);
        }

    // ---- per-batch softmax + PV (Ps reused sequentially) ----
#pragma unroll
    for (int bb = 0; bb < 2; ++bb) {
      float tm[4];
#pragma unroll
      for (int n = 0; n < 4; ++n) {
#pragma unroll
        for (int j = 0; j < 4; ++j) {
          const float mf = (float)((mc[bb][n] >> (8 * j)) & 255u);
          sacc[bb][n][j] = fmaf(mf, -2e9f, fmaf(bc[n][j], LOG2E, sacc[bb][n][j]));
        }
        tm[n] = fmaxf(fmaxf(sacc[bb][n][0], sacc[bb][n][1]),
                      fmaxf(sacc[bb][n][2], sacc[bb][n][3]));
      }
      float tmax = fmaxf(fmaxf(tm[0], tm[1]), fmaxf(tm[2], tm[3]));
      tmax = fmaxf(tmax, __shfl_xor(tmax, 16));
      tmax = fmaxf(tmax, __shfl_xor(tmax, 32));

      // T13 defer-max: skip rescale unless tile max exceeds running max+11.5
      if (!__all(tmax <= mrow[bb] + 11.5f)) {
        const float mnew = fmaxf(mrow[bb], tmax);
        const float alpha = __builtin_exp2f(mrow[bb] - mnew);
        mrow[bb] = mnew;
        lrow[bb] *= alpha;
        float aq[4];
#pragma unroll
        for (int j = 0; j < 4; ++j) aq[j] = __shfl(alpha, l4 * 4 + j);
#pragma unroll
        for (int n = 0; n < 4; ++n)
#pragma unroll
          for (int j = 0; j < 4; ++j) oacc[bb][n][j] *= aq[j];
      }

      float ls[4];
#pragma unroll
      for (int n = 0; n < 4; ++n) {
#pragma unroll
        for (int j = 0; j < 4; ++j)
          sacc[bb][n][j] = __builtin_exp2f(sacc[bb][n][j] - mrow[bb]);
        ls[n] = (sacc[bb][n][0] + sacc[bb][n][1]) + (sacc[bb][n][2] + sacc[bb][n][3]);
      }
      float lsum = (ls[0] + ls[1]) + (ls[2] + ls[3]);
      lsum += __shfl_xor(lsum, 16);
      lsum += __shfl_xor(lsum, 32);
      lrow[bb] += lsum;

      // P -> per-wave LDS (pkrtz pairs, 8B swizzled writes)
#pragma unroll
      for (int n = 0; n < 4; ++n) {
        const h2 p01 = __builtin_amdgcn_cvt_pkrtz(sacc[bb][n][0], sacc[bb][n][1]);
        const h2 p23 = __builtin_amdgcn_cvt_pkrtz(sacc[bb][n][2], sacc[bb][n][3]);
        uint2 pk;
        pk.x = __builtin_bit_cast(unsigned int, p01);
        pk.y = __builtin_bit_cast(unsigned int, p23);
        *(uint2*)((char*)&Ps[w][0] + l15 * 128 +
                  ((32 * n + 8 * l4) ^ ((l15 & 7) << 4))) = pk;
      }

      // O += P.V
      f16x8 pf[2];
#pragma unroll
      for (int ks = 0; ks < 2; ++ks)
        pf[ks] = *swzr(&Ps[w][0], l15, ks * 64 + l4 * 16);
#pragma unroll
      for (int ks = 0; ks < 2; ++ks)
#pragma unroll
        for (int n = 0; n < 4; ++n) {
          const f16x8 vf = *swzr(&Vs[bb][0], n * 16 + l15, ks * 64 + l4 * 16);
          oacc[bb][n] =
              __builtin_amdgcn_mfma_f32_16x16x32_f16(pf[ks], vf, oacc[bb][n], 0, 0, 0);
        }
    }

    __syncthreads();  // all waves done reading Ks/Vs
    if (kt < 31) STAGE(k0 + 64);  // restage freed single buffer
  }
#undef STAGE

  // ---- normalize and store X[b,s,h*64+d] (f16) ----
#pragma unroll
  for (int bb = 0; bb < 2; ++bb) {
    const float inv = 1.0f / lrow[bb];
    float invq[4];
#pragma unroll
    for (int j = 0; j < 4; ++j) invq[j] = __shfl(inv, l4 * 4 + j);
#pragma unroll
    for (int j = 0; j < 4; ++j) {
      const int qrow = q0 + l4 * 4 + j;
#pragma unroll
      for (int n = 0; n < 4; ++n)
        X[((size_t)bb * 2048 + qrow) * 1024 + h * 64 + n * 16 + l15] =
            (f16)(oacc[bb][n][j] * invq[j]);
    }
  }
}

// ---------------- host ------------------------------------------------------
extern "C" void kernel_launch(void* const* d_in, const int* in_sizes, int n_in,
                              void* d_out, int out_size, void* d_ws, size_t ws_size,
                              hipStream_t stream) {
  const float* query = (const float*)d_in[0];
  const float* key_ = (const float*)d_in[1];
  const float* value = (const float*)d_in[2];
  const uint8_t* mask = (const uint8_t*)d_in[3];
  const float* bias = (const float*)d_in[4];
  const float* Wq = (const float*)d_in[5];
  const float* bq = (const float*)d_in[6];
  const float* Wk = (const float*)d_in[7];
  const float* bk = (const float*)d_in[8];
  const float* Wv = (const float*)d_in[9];
  const float* bv = (const float*)d_in[10];
  const float* Wo = (const float*)d_in[11];
  const float* bo = (const float*)d_in[12];

  char* p = (char*)d_ws;
  f16* qh = (f16*)p; p += (size_t)4194304 * 2;   // contiguous cvt dst region:
  f16* kh = (f16*)p; p += (size_t)4194304 * 2;   // qh,kh,vh,wqh,wkh,wvh,woh
  f16* vh = (f16*)p; p += (size_t)4194304 * 2;
  f16* wqh = (f16*)p; p += (size_t)1048576 * 2;
  f16* wkh = (f16*)p; p += (size_t)1048576 * 2;
  f16* wvh = (f16*)p; p += (size_t)1048576 * 2;
  f16* woh = (f16*)p; p += (size_t)1048576 * 2;
  f16* Qp = (f16*)p; p += (size_t)4194304 * 2;
  f16* Kp = (f16*)p; p += (size_t)4194304 * 2;
  f16* Vt = (f16*)p; p += (size_t)4194304 * 2;
  f16* Xh = (f16*)p; p += (size_t)4194304 * 2;
  uint8_t* m8 = (uint8_t*)p; p += (size_t)8388608;
  int* flag = (int*)p; p += 256;
  if (ws_size < (size_t)(p - (char*)d_ws)) return;

  mask_detect<<<1, 256, 0, stream>>>(mask, flag);
  mask_canon<<<8192, 256, 0, stream>>>(mask, m8, flag);

  CvtSrcs cs;
  cs.s[0] = query; cs.s[1] = key_; cs.s[2] = value;
  cs.s[3] = Wq; cs.s[4] = Wk; cs.s[5] = Wv; cs.s[6] = Wo;
  cvt_all<<<16384, 256, 0, stream>>>(cs, qh);

  gemm_qkv<<<1536, 256, 0, stream>>>(qh, kh, vh, wqh, wkh, wvh, bq, bk, bv,
                                     Qp, Kp, Vt);

  attn_fwd<<<512, 256, 0, stream>>>(Qp, Kp, Vt, bias, m8, Xh);

  gemm_out<<<512, 256, 0, stream>>>(Xh, woh, bo, (float*)d_out);
}